// Round 8
// baseline (4172.069 us; speedup 1.0000x reference)
//
#include <hip/hip_runtime.h>
#include <hip/hip_bf16.h>

// Problem constants (fixed shapes per reference setup_inputs; n_step = 200).
#define MM 64
#define NN 4096
#define KK 4096
#define NSTEP 200

typedef __bf16 bf16x8 __attribute__((ext_vector_type(8)));
typedef float  f32x4  __attribute__((ext_vector_type(4)));

static __device__ __forceinline__ unsigned short f2bf(float f) {
    __hip_bfloat16 h = __float2bfloat16(f);
    return __builtin_bit_cast(unsigned short, h);
}
static __device__ __forceinline__ float bf2f(unsigned short u) {
    __hip_bfloat16 h = __builtin_bit_cast(__hip_bfloat16, u);
    return __bfloat162float(h);
}

// Fragment layouts (mfma_f32_16x16x32_bf16, m89 mapping:
//   frag[lane=q*16+l16][j] = Mat[row16=l16][k=q*8+j]):
// A (g):  addr(m,kg) = ((kc*4 + (m>>4))*64 + q*16 + (m&15))*8 + j
// B (W):  addr(n,kg) = (((n>>4)*128 + kc)*64 + q*16 + (n&15))*8 + j

// ---------------------------------------------------------------------------
// Prologue 1: s = 0.5*(W[n][k]+W[k][n]), diag zero; (hi,lo) bf16 split,
// scattered into B-fragment order. 64x64 tiles, LDS transpose.
// ---------------------------------------------------------------------------
__global__ __launch_bounds__(256) void symm_kernel(const float* __restrict__ W,
                                                   unsigned short* __restrict__ Wfh,
                                                   unsigned short* __restrict__ Wfl) {
    __shared__ float T[64][65];
    const int tid = threadIdx.x;
    const int r0 = blockIdx.y * 64, c0 = blockIdx.x * 64;
#pragma unroll
    for (int i = 0; i < 4; ++i) {
        int lin = tid + i * 256;
        int cc  = lin >> 4;
        int r4  = (lin & 15) * 4;
        float4 v = *(const float4*)&W[(size_t)(c0 + cc) * NN + r0 + r4];
        T[cc][r4 + 0] = v.x; T[cc][r4 + 1] = v.y;
        T[cc][r4 + 2] = v.z; T[cc][r4 + 3] = v.w;
    }
    __syncthreads();
#pragma unroll
    for (int i = 0; i < 4; ++i) {
        int lin = tid + i * 256;
        int rr  = lin >> 4;
        int c4  = (lin & 15) * 4;
        float4 v = *(const float4*)&W[(size_t)(r0 + rr) * NN + c0 + c4];
        float d[4] = {v.x, v.y, v.z, v.w};
        ushort4 ohi, olo;
        unsigned short* ph = (unsigned short*)&ohi;
        unsigned short* pl = (unsigned short*)&olo;
#pragma unroll
        for (int j = 0; j < 4; ++j) {
            float sv = 0.5f * (d[j] + T[c4 + j][rr]);
            if (r0 + rr == c0 + c4 + j) sv = 0.0f;
            unsigned short hi = f2bf(sv);
            ph[j] = hi;
            pl[j] = f2bf(sv - bf2f(hi));
        }
        const int n  = r0 + rr;            // W row == output column
        const int kg = c0 + c4;            // 4-aligned
        const int s16 = n >> 4, ln = n & 15;
        const int kc = kg >> 5, q = (kg & 31) >> 3, j0 = kg & 7;
        size_t off = (((size_t)s16 * 128 + kc) * 64 + q * 16 + ln) * 8 + j0;
        *(ushort4*)&Wfh[off] = ohi;        // 8B-aligned
        *(ushort4*)&Wfl[off] = olo;
    }
}

// ---------------------------------------------------------------------------
// Prologue 2: x0 = (1/beta)*log(g/(1-g)) (plain layout); g -> A-frag (hi,lo)
// ---------------------------------------------------------------------------
__global__ __launch_bounds__(256) void init_kernel(const float* __restrict__ g_in,
                                                   const float* __restrict__ beta,
                                                   float* __restrict__ x,
                                                   unsigned short* __restrict__ gfh,
                                                   unsigned short* __restrict__ gfl) {
    int idx = blockIdx.x * 256 + threadIdx.x;
    int r = idx >> 12, c = idx & (NN - 1);
    float g = g_in[idx];
    x[idx] = logf(g / (1.0f - g)) / beta[c];
    unsigned short hi = f2bf(g);
    unsigned short lo = f2bf(g - bf2f(hi));
    size_t off = (((size_t)(c >> 5) * 4 + (r >> 4)) * 64 + ((c & 31) >> 3) * 16 + (r & 15)) * 8 + (c & 7);
    gfh[off] = hi;
    gfl[off] = lo;
}

// ---------------------------------------------------------------------------
// Prologue 3: max_x = 50 / max(beta)
// ---------------------------------------------------------------------------
__global__ __launch_bounds__(256) void maxx_kernel(const float* __restrict__ beta,
                                                   float* __restrict__ out) {
    __shared__ float red[256];
    float m = -1e30f;
    for (int i = threadIdx.x; i < NN; i += 256) m = fmaxf(m, beta[i]);
    red[threadIdx.x] = m;
    __syncthreads();
    for (int s = 128; s > 0; s >>= 1) {
        if (threadIdx.x < s) red[threadIdx.x] = fmaxf(red[threadIdx.x], red[threadIdx.x + s]);
        __syncthreads();
    }
    if (threadIdx.x == 0) out[0] = 50.0f / red[0];
}

// ---------------------------------------------------------------------------
// GEMM kernel v5: distinct-optimal reads. v2/v4 both plateaued at ~17.8
// us/step with IDENTICAL total vector-memory traffic (320 MB/step): each
// wave re-fetched A-fragments per MFMA iteration -> 4x redundancy via L2.
// v5 re-maps wave->work: grid 256 = 64 strips (64 cols) x 4 K-quarters;
// wave w (of 16) owns a 64-k slice (2 x 32-k chunks) and computes ALL 64
// cols x 4 m-subtiles (acc[4][4]). Per-block reads = 256 KB A + 256 KB W
// = exactly the distinct data (128 MB/step total, 2.5x less than v4).
// Per it: 16 loads feed 48 MFMAs (was 10:12).
// 16-way K-reduction via two-stage LDS (128 KB): waves 0-7 dump, waves
// 8-15 add in-place, then 8-way reduce -> P. No cross-block sync (v3's
// fence+atomic cost 180 us/step; kernel boundary is the barrier).
// ---------------------------------------------------------------------------
__global__ __launch_bounds__(1024, 1) void gemm_kernel(
    const unsigned short* __restrict__ gfh,
    const unsigned short* __restrict__ gfl,
    const unsigned short* __restrict__ Wfh,
    const unsigned short* __restrict__ Wfl,
    float* __restrict__ P)                    // [4][64][64][64] fp32 partials
{
    __shared__ float sacc[8][16][64][4];      // 128 KB: [slice][frag][lane][reg]

    const int tid  = threadIdx.x;
    const int w    = tid >> 6;                // k-slice 0..15 (64 k each)
    const int lane = tid & 63;
    const int s64  = blockIdx.x >> 2;         // 64-col strip 0..63
    const int kq   = blockIdx.x & 3;          // K-quarter 0..3 (1024 k)

    f32x4 acc[4][4] = {};                     // [mq][nq] 16x16 frags

#pragma unroll
    for (int it = 0; it < 2; ++it) {
        const int kc = kq * 32 + w * 2 + it;  // 32-wide K chunk
        bf16x8 ah[4], al[4], bh[4], bl[4];
#pragma unroll
        for (int mq = 0; mq < 4; ++mq) {
            const size_t a = ((size_t)kc * 4 + mq) * 512 + lane * 8;
            ah[mq] = *(const bf16x8*)&gfh[a];
            al[mq] = *(const bf16x8*)&gfl[a];
        }
#pragma unroll
        for (int nq = 0; nq < 4; ++nq) {
            const size_t b = (((size_t)(s64 * 4 + nq) * 128 + kc) * 64 + lane) * 8;
            bh[nq] = *(const bf16x8*)&Wfh[b];
            bl[nq] = *(const bf16x8*)&Wfl[b];
        }
#pragma unroll
        for (int mq = 0; mq < 4; ++mq)
#pragma unroll
            for (int nq = 0; nq < 4; ++nq) {
                acc[mq][nq] = __builtin_amdgcn_mfma_f32_16x16x32_bf16(ah[mq], bh[nq], acc[mq][nq], 0, 0, 0);
                acc[mq][nq] = __builtin_amdgcn_mfma_f32_16x16x32_bf16(al[mq], bh[nq], acc[mq][nq], 0, 0, 0);
                acc[mq][nq] = __builtin_amdgcn_mfma_f32_16x16x32_bf16(ah[mq], bl[nq], acc[mq][nq], 0, 0, 0);
            }
    }

    // Stage 1: waves 0-7 dump their accumulators (b128 stores, lane-major).
    if (w < 8) {
#pragma unroll
        for (int mq = 0; mq < 4; ++mq)
#pragma unroll
            for (int nq = 0; nq < 4; ++nq)
                *(f32x4*)&sacc[w][mq * 4 + nq][lane][0] = acc[mq][nq];
    }
    __syncthreads();
    // Stage 2: waves 8-15 add in-place into slice w-8 (disjoint per wave).
    if (w >= 8) {
#pragma unroll
        for (int mq = 0; mq < 4; ++mq)
#pragma unroll
            for (int nq = 0; nq < 4; ++nq) {
                f32x4 old = *(const f32x4*)&sacc[w - 8][mq * 4 + nq][lane][0];
                *(f32x4*)&sacc[w - 8][mq * 4 + nq][lane][0] = old + acc[mq][nq];
            }
    }
    __syncthreads();

    // Stage 3: 8-way reduce -> P[kq][s64][64 rows][64 cols].
    // Thread t: row m = t>>4, cols c = (t&15)*4 .. +3 (float4 store).
    // C-frag layout: value(row16=q*4+rg, col=l16) at lane q*16+l16, reg rg.
    {
        const int m  = tid >> 4;
        const int tt = tid & 15;
        const int mq = m >> 4, q = (m & 15) >> 2, rg = m & 3;
        const int nq = tt >> 2;               // (c>>4) for c = tt*4+j
        const int fi = mq * 4 + nq;
        float4 pv;
#pragma unroll
        for (int j = 0; j < 4; ++j) {
            const int cl = q * 16 + (tt & 3) * 4 + j;
            float v = 0.0f;
#pragma unroll
            for (int kh = 0; kh < 8; ++kh)
                v += sacc[kh][fi][cl][rg];
            (&pv.x)[j] = v;
        }
        *(float4*)&P[(((size_t)(kq * 64 + s64) * 64 + m) * 64) + tt * 4] = pv;
    }
}

// ---------------------------------------------------------------------------
// Epilogue kernel: grid 256 x 256 thr; block b -> strip s64 = b>>2,
// row-quarter mq4 = b&3. Thread t: row, 4 cols. Sums 4 K-quarter partials,
// applies b/alpha/clip/sigmoid, updates x, writes next-step A-fragments.
// Cross-kernel P visibility via the dispatch boundary (baseline-proven).
// ---------------------------------------------------------------------------
__global__ __launch_bounds__(256) void epi_kernel(
    const float* __restrict__ P,
    float* __restrict__ x,
    unsigned short* __restrict__ gfh_out,
    unsigned short* __restrict__ gfl_out,
    const float* __restrict__ bvec,
    const float* __restrict__ beta,
    const float* __restrict__ tau,
    const float* __restrict__ dt_ptr,
    const float* __restrict__ maxx_ptr,
    float* __restrict__ gout_f32)             // non-null on last step only
{
    const int tid = threadIdx.x;
    const int s64 = blockIdx.x >> 2;
    const int mq4 = blockIdx.x & 3;
    const int m   = mq4 * 16 + (tid >> 4);    // batch row 0..63
    const int tt  = tid & 15;
    const int c0  = tt * 4;
    const int n0  = s64 * 64 + c0;            // global col, 4-aligned

    const size_t pb = ((size_t)s64 * 64 + m) * 64 + c0;
    float4 p0 = *(const float4*)&P[pb];
    float4 p1 = *(const float4*)&P[(size_t)(1 * 64) * 4096 + pb];
    float4 p2 = *(const float4*)&P[(size_t)(2 * 64) * 4096 + pb];
    float4 p3 = *(const float4*)&P[(size_t)(3 * 64) * 4096 + pb];
    float sum[4] = {p0.x + p1.x + p2.x + p3.x,
                    p0.y + p1.y + p2.y + p3.y,
                    p0.z + p1.z + p2.z + p3.z,
                    p0.w + p1.w + p2.w + p3.w};

    const float dt = *dt_ptr;
    const float mx = *maxx_ptr;
    float4 b0 = *(const float4*)&bvec[n0];
    float4 e0 = *(const float4*)&beta[n0];
    float4 t0 = *(const float4*)&tau[n0];
    float bb[4] = {b0.x, b0.y, b0.z, b0.w};
    float be[4] = {e0.x, e0.y, e0.z, e0.w};
    float tv[4] = {t0.x, t0.y, t0.z, t0.w};

    float* xp = &x[(size_t)m * NN + n0];
    float4 x0 = *(const float4*)xp;
    float xo[4] = {x0.x, x0.y, x0.z, x0.w};

    float gg[4];
    unsigned short vh[4], vl[4];
#pragma unroll
    for (int j = 0; j < 4; ++j) {
        const float al = dt / tv[j];
        float xn = al * (sum[j] + bb[j]) + (1.0f - al) * xo[j];
        xn = fminf(fmaxf(xn, -mx), mx);
        float g = 1.0f / (1.0f + __expf(-be[j] * xn));
        xo[j] = xn;
        gg[j] = g;
        unsigned short hi = f2bf(g);
        vh[j] = hi;
        vl[j] = f2bf(g - bf2f(hi));
    }
    *(float4*)xp = {xo[0], xo[1], xo[2], xo[3]};

    // A-fragment scatter for (m, kg = n0..n0+3); n0%8 in {0,4} -> ushort4.
    size_t off = (((size_t)(n0 >> 5) * 4 + (m >> 4)) * 64 + ((n0 & 31) >> 3) * 16 + (m & 15)) * 8 + (n0 & 7);
    *(ushort4*)&gfh_out[off] = {vh[0], vh[1], vh[2], vh[3]};
    *(ushort4*)&gfl_out[off] = {vl[0], vl[1], vl[2], vl[3]};

    if (gout_f32)
        *(float4*)&gout_f32[(size_t)m * NN + n0] = {gg[0], gg[1], gg[2], gg[3]};
}

// ---------------------------------------------------------------------------
extern "C" void kernel_launch(void* const* d_in, const int* in_sizes, int n_in,
                              void* d_out, int out_size, void* d_ws, size_t ws_size,
                              hipStream_t stream) {
    const float* state_g = (const float*)d_in[0];
    const float* W       = (const float*)d_in[1];
    const float* b       = (const float*)d_in[2];
    const float* beta    = (const float*)d_in[3];
    const float* tau     = (const float*)d_in[4];
    const float* dt      = (const float*)d_in[5];
    float* out = (float*)d_out;

    char* ws = (char*)d_ws;
    const size_t WH = (size_t)KK * NN * 2;    // 32 MB per W-frag array
    const size_t XB = (size_t)MM * NN * 4;    // 1 MB
    const size_t GB = (size_t)MM * NN * 2;    // 512 KB per g-frag array
    const size_t PB = (size_t)4 * 64 * 64 * 64 * 4;   // 4 MB partials
    unsigned short* Wfh = (unsigned short*)ws;
    unsigned short* Wfl = (unsigned short*)(ws + WH);
    float*          x   = (float*)(ws + 2 * WH);
    unsigned short* g0h = (unsigned short*)(ws + 2 * WH + XB);
    unsigned short* g0l = (unsigned short*)(ws + 2 * WH + XB + GB);
    unsigned short* g1h = (unsigned short*)(ws + 2 * WH + XB + 2 * GB);
    unsigned short* g1l = (unsigned short*)(ws + 2 * WH + XB + 3 * GB);
    float*          P   = (float*)(ws + 2 * WH + XB + 4 * GB);
    float*          mxp = (float*)(ws + 2 * WH + XB + 4 * GB + PB);

    symm_kernel<<<dim3(64, 64), 256, 0, stream>>>(W, Wfh, Wfl);
    init_kernel<<<(MM * NN) / 256, 256, 0, stream>>>(state_g, beta, x, g0h, g0l);
    maxx_kernel<<<1, 256, 0, stream>>>(beta, mxp);

    unsigned short *gih = g0h, *gil = g0l, *goh = g1h, *gol = g1l;
    for (int st = 0; st < NSTEP; ++st) {
        float* of = (st == NSTEP - 1) ? out : nullptr;
        gemm_kernel<<<256, 1024, 0, stream>>>(gih, gil, Wfh, Wfl, P);
        epi_kernel<<<256, 256, 0, stream>>>(P, x, goh, gol, b, beta, tau, dt, mxp, of);
        unsigned short* tp;
        tp = gih; gih = goh; goh = tp;
        tp = gil; gil = gol; gol = tp;
    }
}

// Round 9
// 3728.325 us; speedup vs baseline: 1.1190x; 1.1190x over previous
//
#include <hip/hip_runtime.h>
#include <hip/hip_bf16.h>

// Problem constants (fixed shapes per reference setup_inputs; n_step = 200).
#define MM 64
#define NN 4096
#define KK 4096
#define NSTEP 200

typedef __bf16 bf16x8 __attribute__((ext_vector_type(8)));
typedef float  f32x4  __attribute__((ext_vector_type(4)));

static __device__ __forceinline__ unsigned short f2bf(float f) {
    __hip_bfloat16 h = __float2bfloat16(f);
    return __builtin_bit_cast(unsigned short, h);
}
static __device__ __forceinline__ float bf2f(unsigned short u) {
    __hip_bfloat16 h = __builtin_bit_cast(__hip_bfloat16, u);
    return __bfloat162float(h);
}

// Fragment layouts (mfma_f32_16x16x32_bf16, m89 mapping:
//   frag[lane=q*16+l16][j] = Mat[row16=l16][k=q*8+j]):
// A (g):  addr(m,kg) = ((kc*4 + (m>>4))*64 + q*16 + (m&15))*8 + j
// B (W):  addr(n,kg) = (((n>>4)*128 + kc)*64 + q*16 + (n&15))*8 + j

// ---------------------------------------------------------------------------
// Prologue 1: s = 0.5*(W[n][k]+W[k][n]), diag zero; (hi,lo) bf16 split,
// scattered into B-fragment order. 64x64 tiles, LDS transpose.
// ---------------------------------------------------------------------------
__global__ __launch_bounds__(256) void symm_kernel(const float* __restrict__ W,
                                                   unsigned short* __restrict__ Wfh,
                                                   unsigned short* __restrict__ Wfl) {
    __shared__ float T[64][65];
    const int tid = threadIdx.x;
    const int r0 = blockIdx.y * 64, c0 = blockIdx.x * 64;
#pragma unroll
    for (int i = 0; i < 4; ++i) {
        int lin = tid + i * 256;
        int cc  = lin >> 4;
        int r4  = (lin & 15) * 4;
        float4 v = *(const float4*)&W[(size_t)(c0 + cc) * NN + r0 + r4];
        T[cc][r4 + 0] = v.x; T[cc][r4 + 1] = v.y;
        T[cc][r4 + 2] = v.z; T[cc][r4 + 3] = v.w;
    }
    __syncthreads();
#pragma unroll
    for (int i = 0; i < 4; ++i) {
        int lin = tid + i * 256;
        int rr  = lin >> 4;
        int c4  = (lin & 15) * 4;
        float4 v = *(const float4*)&W[(size_t)(r0 + rr) * NN + c0 + c4];
        float d[4] = {v.x, v.y, v.z, v.w};
        ushort4 ohi, olo;
        unsigned short* ph = (unsigned short*)&ohi;
        unsigned short* pl = (unsigned short*)&olo;
#pragma unroll
        for (int j = 0; j < 4; ++j) {
            float sv = 0.5f * (d[j] + T[c4 + j][rr]);
            if (r0 + rr == c0 + c4 + j) sv = 0.0f;
            unsigned short hi = f2bf(sv);
            ph[j] = hi;
            pl[j] = f2bf(sv - bf2f(hi));
        }
        const int n  = r0 + rr;            // W row == output column
        const int kg = c0 + c4;            // 4-aligned
        const int s16 = n >> 4, ln = n & 15;
        const int kc = kg >> 5, q = (kg & 31) >> 3, j0 = kg & 7;
        size_t off = (((size_t)s16 * 128 + kc) * 64 + q * 16 + ln) * 8 + j0;
        *(ushort4*)&Wfh[off] = ohi;        // 8B-aligned
        *(ushort4*)&Wfl[off] = olo;
    }
}

// ---------------------------------------------------------------------------
// Prologue 2: x0 = (1/beta)*log(g/(1-g)) (plain layout); g -> A-frag (hi,lo)
// ---------------------------------------------------------------------------
__global__ __launch_bounds__(256) void init_kernel(const float* __restrict__ g_in,
                                                   const float* __restrict__ beta,
                                                   float* __restrict__ x,
                                                   unsigned short* __restrict__ gfh,
                                                   unsigned short* __restrict__ gfl) {
    int idx = blockIdx.x * 256 + threadIdx.x;
    int r = idx >> 12, c = idx & (NN - 1);
    float g = g_in[idx];
    x[idx] = logf(g / (1.0f - g)) / beta[c];
    unsigned short hi = f2bf(g);
    unsigned short lo = f2bf(g - bf2f(hi));
    size_t off = (((size_t)(c >> 5) * 4 + (r >> 4)) * 64 + ((c & 31) >> 3) * 16 + (r & 15)) * 8 + (c & 7);
    gfh[off] = hi;
    gfl[off] = lo;
}

// ---------------------------------------------------------------------------
// Prologue 3: max_x = 50 / max(beta)
// ---------------------------------------------------------------------------
__global__ __launch_bounds__(256) void maxx_kernel(const float* __restrict__ beta,
                                                   float* __restrict__ out) {
    __shared__ float red[256];
    float m = -1e30f;
    for (int i = threadIdx.x; i < NN; i += 256) m = fmaxf(m, beta[i]);
    red[threadIdx.x] = m;
    __syncthreads();
    for (int s = 128; s > 0; s >>= 1) {
        if (threadIdx.x < s) red[threadIdx.x] = fmaxf(red[threadIdx.x], red[threadIdx.x + s]);
        __syncthreads();
    }
    if (threadIdx.x == 0) out[0] = 50.0f / red[0];
}

// ---------------------------------------------------------------------------
// GEMM kernel v6: 2 blocks/CU. Evidence: baseline/v2/v4/v5 all plateau at
// ~18 us/step despite 128-320 MB/step traffic differences -> traffic-volume
// theories falsified; the invariant is grid=256 (1 big block/CU) with a
// serial LDS-reduce + P-store tail and latency-exposed load head (v3 profile:
// 27% occupancy). v6 halves the block (512 thr, 8 waves), doubles the grid
// (512 = 64 strips x 8 K-eighths): LDS 67->17 KB, __launch_bounds__(512,4)
// => 2 co-resident blocks/CU so one block's MFMA overlaps the other's tail.
// Per-wave inner loop byte-identical to v4 (verified absmax 0.00390625):
// wave w: nq=w&3 (16-col group), kh=w>>2 (256-k half of the 512-k eighth).
// kq8 = bx&7 == XCD id -> each XCD's 64 blocks share ONE 128 KB A-eighth
// (L2-pinned). 2-way LDS reduce (kh pairs); P has 8 partials (epi sums 8,
// proven cheap in the original baseline). No cross-block sync (v3 lesson:
// fence+atomic = 180 us/step; kernel boundary is the barrier).
// ---------------------------------------------------------------------------
__global__ __launch_bounds__(512, 4) void gemm_kernel(
    const unsigned short* __restrict__ gfh,
    const unsigned short* __restrict__ gfl,
    const unsigned short* __restrict__ Wfh,
    const unsigned short* __restrict__ Wfl,
    float* __restrict__ P)                    // [8][64][64][64] fp32 partials
{
    __shared__ float sacc[4][16][65];         // 16.6 KB: [nq][mq*4+rg][lane]

    const int tid  = threadIdx.x;
    const int w    = tid >> 6;                // 0..7
    const int lane = tid & 63;
    const int s64  = blockIdx.x >> 3;         // 64-col strip 0..63
    const int kq8  = blockIdx.x & 7;          // K-eighth 0..7 (512 k)
    const int nq   = w & 3;                   // wave's 16-col group in strip
    const int kh   = w >> 2;                  // wave's 256-k half

    f32x4 acc[4] = {};                        // 4 m-subtiles x (16x16) frag

#pragma unroll
    for (int it = 0; it < 8; ++it) {
        const int kc = kq8 * 16 + kh * 8 + it;       // 32-wide K chunk
        const size_t aBase = (size_t)kc * 2048 + lane * 8;          // + mq*512
        const size_t bOff  = (((size_t)(s64 * 4 + nq) * 128 + kc) * 64 + lane) * 8;
        bf16x8 bh = *(const bf16x8*)&Wfh[bOff];
        bf16x8 bl = *(const bf16x8*)&Wfl[bOff];
        bf16x8 ah[4], al[4];
#pragma unroll
        for (int mq = 0; mq < 4; ++mq) {
            ah[mq] = *(const bf16x8*)&gfh[aBase + (size_t)mq * 512];
            al[mq] = *(const bf16x8*)&gfl[aBase + (size_t)mq * 512];
        }
#pragma unroll
        for (int mq = 0; mq < 4; ++mq) {
            acc[mq] = __builtin_amdgcn_mfma_f32_16x16x32_bf16(ah[mq], bh, acc[mq], 0, 0, 0);
            acc[mq] = __builtin_amdgcn_mfma_f32_16x16x32_bf16(al[mq], bh, acc[mq], 0, 0, 0);
            acc[mq] = __builtin_amdgcn_mfma_f32_16x16x32_bf16(ah[mq], bl, acc[mq], 0, 0, 0);
        }
    }

    // kh=0 waves dump (w == nq for w<4); kh=1 waves add in-place.
    if (kh == 0) {
#pragma unroll
        for (int mq = 0; mq < 4; ++mq)
#pragma unroll
            for (int rg = 0; rg < 4; ++rg)
                sacc[w][mq * 4 + rg][lane] = acc[mq][rg];
    }
    __syncthreads();
    if (kh == 1) {
#pragma unroll
        for (int mq = 0; mq < 4; ++mq)
#pragma unroll
            for (int rg = 0; rg < 4; ++rg)
                sacc[w - 4][mq * 4 + rg][lane] += acc[mq][rg];
    }
    __syncthreads();

    // P write: 512 threads x 8 floats. Thread t: row m = t>>3, cols
    // c = (t&7)*8 .. +7 (two float4). C-frag layout: value(row16=q*4+rg,
    // col16=l16) at sacc[nq][mq*4+rg][q*16+l16].
    {
        const int m   = tid >> 3;
        const int tt  = tid & 7;
        const int mq  = m >> 4, q = (m & 15) >> 2, rg = m & 3;
        const int ridx = mq * 4 + rg;
        const int nqc  = tt >> 1;             // (c>>4), constant over the 8 cols
        const int l0   = (tt & 1) * 8;        // base l16
        float4 pv0, pv1;
#pragma unroll
        for (int j = 0; j < 4; ++j) {
            (&pv0.x)[j] = sacc[nqc][ridx][q * 16 + l0 + j];
            (&pv1.x)[j] = sacc[nqc][ridx][q * 16 + l0 + 4 + j];
        }
        const size_t pb = (((size_t)(kq8 * 64 + s64) * 64 + m) * 64) + tt * 8;
        *(float4*)&P[pb]     = pv0;
        *(float4*)&P[pb + 4] = pv1;
    }
}

// ---------------------------------------------------------------------------
// Epilogue kernel: grid 256 x 256 thr; block b -> strip s64 = b>>2,
// row-quarter mq4 = b&3. Thread t: row, 4 cols. Sums 8 K-eighth partials,
// applies b/alpha/clip/sigmoid, updates x, writes next-step A-fragments.
// Cross-kernel P visibility via the dispatch boundary (baseline-proven).
// ---------------------------------------------------------------------------
__global__ __launch_bounds__(256) void epi_kernel(
    const float* __restrict__ P,
    float* __restrict__ x,
    unsigned short* __restrict__ gfh_out,
    unsigned short* __restrict__ gfl_out,
    const float* __restrict__ bvec,
    const float* __restrict__ beta,
    const float* __restrict__ tau,
    const float* __restrict__ dt_ptr,
    const float* __restrict__ maxx_ptr,
    float* __restrict__ gout_f32)             // non-null on last step only
{
    const int tid = threadIdx.x;
    const int s64 = blockIdx.x >> 2;
    const int mq4 = blockIdx.x & 3;
    const int m   = mq4 * 16 + (tid >> 4);    // batch row 0..63
    const int tt  = tid & 15;
    const int c0  = tt * 4;
    const int n0  = s64 * 64 + c0;            // global col, 4-aligned

    const size_t pb = ((size_t)s64 * 64 + m) * 64 + c0;
    float sum[4] = {};
#pragma unroll
    for (int k8 = 0; k8 < 8; ++k8) {
        float4 p = *(const float4*)&P[(size_t)k8 * 262144 + pb];
        sum[0] += p.x; sum[1] += p.y; sum[2] += p.z; sum[3] += p.w;
    }

    const float dt = *dt_ptr;
    const float mx = *maxx_ptr;
    float4 b0 = *(const float4*)&bvec[n0];
    float4 e0 = *(const float4*)&beta[n0];
    float4 t0 = *(const float4*)&tau[n0];
    float bb[4] = {b0.x, b0.y, b0.z, b0.w};
    float be[4] = {e0.x, e0.y, e0.z, e0.w};
    float tv[4] = {t0.x, t0.y, t0.z, t0.w};

    float* xp = &x[(size_t)m * NN + n0];
    float4 x0 = *(const float4*)xp;
    float xo[4] = {x0.x, x0.y, x0.z, x0.w};

    float gg[4];
    unsigned short vh[4], vl[4];
#pragma unroll
    for (int j = 0; j < 4; ++j) {
        const float al = dt / tv[j];
        float xn = al * (sum[j] + bb[j]) + (1.0f - al) * xo[j];
        xn = fminf(fmaxf(xn, -mx), mx);
        float g = 1.0f / (1.0f + __expf(-be[j] * xn));
        xo[j] = xn;
        gg[j] = g;
        unsigned short hi = f2bf(g);
        vh[j] = hi;
        vl[j] = f2bf(g - bf2f(hi));
    }
    *(float4*)xp = {xo[0], xo[1], xo[2], xo[3]};

    // A-fragment scatter for (m, kg = n0..n0+3); n0%8 in {0,4} -> ushort4.
    size_t off = (((size_t)(n0 >> 5) * 4 + (m >> 4)) * 64 + ((n0 & 31) >> 3) * 16 + (m & 15)) * 8 + (n0 & 7);
    *(ushort4*)&gfh_out[off] = {vh[0], vh[1], vh[2], vh[3]};
    *(ushort4*)&gfl_out[off] = {vl[0], vl[1], vl[2], vl[3]};

    if (gout_f32)
        *(float4*)&gout_f32[(size_t)m * NN + n0] = {gg[0], gg[1], gg[2], gg[3]};
}

// ---------------------------------------------------------------------------
extern "C" void kernel_launch(void* const* d_in, const int* in_sizes, int n_in,
                              void* d_out, int out_size, void* d_ws, size_t ws_size,
                              hipStream_t stream) {
    const float* state_g = (const float*)d_in[0];
    const float* W       = (const float*)d_in[1];
    const float* b       = (const float*)d_in[2];
    const float* beta    = (const float*)d_in[3];
    const float* tau     = (const float*)d_in[4];
    const float* dt      = (const float*)d_in[5];
    float* out = (float*)d_out;

    char* ws = (char*)d_ws;
    const size_t WH = (size_t)KK * NN * 2;    // 32 MB per W-frag array
    const size_t XB = (size_t)MM * NN * 4;    // 1 MB
    const size_t GB = (size_t)MM * NN * 2;    // 512 KB per g-frag array
    const size_t PB = (size_t)8 * 64 * 64 * 64 * 4;   // 8 MB partials
    unsigned short* Wfh = (unsigned short*)ws;
    unsigned short* Wfl = (unsigned short*)(ws + WH);
    float*          x   = (float*)(ws + 2 * WH);
    unsigned short* g0h = (unsigned short*)(ws + 2 * WH + XB);
    unsigned short* g0l = (unsigned short*)(ws + 2 * WH + XB + GB);
    unsigned short* g1h = (unsigned short*)(ws + 2 * WH + XB + 2 * GB);
    unsigned short* g1l = (unsigned short*)(ws + 2 * WH + XB + 3 * GB);
    float*          P   = (float*)(ws + 2 * WH + XB + 4 * GB);
    float*          mxp = (float*)(ws + 2 * WH + XB + 4 * GB + PB);

    symm_kernel<<<dim3(64, 64), 256, 0, stream>>>(W, Wfh, Wfl);
    init_kernel<<<(MM * NN) / 256, 256, 0, stream>>>(state_g, beta, x, g0h, g0l);
    maxx_kernel<<<1, 256, 0, stream>>>(beta, mxp);

    unsigned short *gih = g0h, *gil = g0l, *goh = g1h, *gol = g1l;
    for (int st = 0; st < NSTEP; ++st) {
        float* of = (st == NSTEP - 1) ? out : nullptr;
        gemm_kernel<<<512, 512, 0, stream>>>(gih, gil, Wfh, Wfl, P);
        epi_kernel<<<256, 256, 0, stream>>>(P, x, goh, gol, b, beta, tau, dt, mxp, of);
        unsigned short* tp;
        tp = gih; gih = goh; goh = tp;
        tp = gil; gil = gol; gol = tp;
    }
}

// Round 10
// 3350.412 us; speedup vs baseline: 1.2452x; 1.1128x over previous
//
#include <hip/hip_runtime.h>
#include <hip/hip_bf16.h>

// Problem constants (fixed shapes per reference setup_inputs; n_step = 200).
#define MM 64
#define NN 4096
#define KK 4096
#define NSTEP 200

typedef __bf16 bf16x8 __attribute__((ext_vector_type(8)));
typedef float  f32x4  __attribute__((ext_vector_type(4)));

static __device__ __forceinline__ unsigned short f2bf(float f) {
    __hip_bfloat16 h = __float2bfloat16(f);
    return __builtin_bit_cast(unsigned short, h);
}
static __device__ __forceinline__ float bf2f(unsigned short u) {
    __hip_bfloat16 h = __builtin_bit_cast(__hip_bfloat16, u);
    return __bfloat162float(h);
}

// Fragment layouts (mfma_f32_16x16x32_bf16, m89 mapping:
//   frag[lane=q*16+l16][j] = Mat[row16=l16][k=q*8+j]):
// A (g):  addr(m,kg) = ((kc*4 + (m>>4))*64 + q*16 + (m&15))*8 + j
// B (W):  addr(n,kg) = (((n>>4)*128 + kc)*64 + q*16 + (n&15))*8 + j

// ---------------------------------------------------------------------------
// Prologue 1: s = 0.5*(W[n][k]+W[k][n]), diag zero; (hi,lo) bf16 split,
// scattered into B-fragment order. 64x64 tiles, LDS transpose.
// ---------------------------------------------------------------------------
__global__ __launch_bounds__(256) void symm_kernel(const float* __restrict__ W,
                                                   unsigned short* __restrict__ Wfh,
                                                   unsigned short* __restrict__ Wfl) {
    __shared__ float T[64][65];
    const int tid = threadIdx.x;
    const int r0 = blockIdx.y * 64, c0 = blockIdx.x * 64;
#pragma unroll
    for (int i = 0; i < 4; ++i) {
        int lin = tid + i * 256;
        int cc  = lin >> 4;
        int r4  = (lin & 15) * 4;
        float4 v = *(const float4*)&W[(size_t)(c0 + cc) * NN + r0 + r4];
        T[cc][r4 + 0] = v.x; T[cc][r4 + 1] = v.y;
        T[cc][r4 + 2] = v.z; T[cc][r4 + 3] = v.w;
    }
    __syncthreads();
#pragma unroll
    for (int i = 0; i < 4; ++i) {
        int lin = tid + i * 256;
        int rr  = lin >> 4;
        int c4  = (lin & 15) * 4;
        float4 v = *(const float4*)&W[(size_t)(r0 + rr) * NN + c0 + c4];
        float d[4] = {v.x, v.y, v.z, v.w};
        ushort4 ohi, olo;
        unsigned short* ph = (unsigned short*)&ohi;
        unsigned short* pl = (unsigned short*)&olo;
#pragma unroll
        for (int j = 0; j < 4; ++j) {
            float sv = 0.5f * (d[j] + T[c4 + j][rr]);
            if (r0 + rr == c0 + c4 + j) sv = 0.0f;
            unsigned short hi = f2bf(sv);
            ph[j] = hi;
            pl[j] = f2bf(sv - bf2f(hi));
        }
        const int n  = r0 + rr;            // W row == output column
        const int kg = c0 + c4;            // 4-aligned
        const int s16 = n >> 4, ln = n & 15;
        const int kc = kg >> 5, q = (kg & 31) >> 3, j0 = kg & 7;
        size_t off = (((size_t)s16 * 128 + kc) * 64 + q * 16 + ln) * 8 + j0;
        *(ushort4*)&Wfh[off] = ohi;        // 8B-aligned
        *(ushort4*)&Wfl[off] = olo;
    }
}

// ---------------------------------------------------------------------------
// Prologue 2: x0 = (1/beta)*log(g/(1-g)) (plain layout); g -> A-frag (hi,lo)
// ---------------------------------------------------------------------------
__global__ __launch_bounds__(256) void init_kernel(const float* __restrict__ g_in,
                                                   const float* __restrict__ beta,
                                                   float* __restrict__ x,
                                                   unsigned short* __restrict__ gfh,
                                                   unsigned short* __restrict__ gfl) {
    int idx = blockIdx.x * 256 + threadIdx.x;
    int r = idx >> 12, c = idx & (NN - 1);
    float g = g_in[idx];
    x[idx] = logf(g / (1.0f - g)) / beta[c];
    unsigned short hi = f2bf(g);
    unsigned short lo = f2bf(g - bf2f(hi));
    size_t off = (((size_t)(c >> 5) * 4 + (r >> 4)) * 64 + ((c & 31) >> 3) * 16 + (r & 15)) * 8 + (c & 7);
    gfh[off] = hi;
    gfl[off] = lo;
}

// ---------------------------------------------------------------------------
// Prologue 3: max_x = 50 / max(beta)
// ---------------------------------------------------------------------------
__global__ __launch_bounds__(256) void maxx_kernel(const float* __restrict__ beta,
                                                   float* __restrict__ out) {
    __shared__ float red[256];
    float m = -1e30f;
    for (int i = threadIdx.x; i < NN; i += 256) m = fmaxf(m, beta[i]);
    red[threadIdx.x] = m;
    __syncthreads();
    for (int s = 128; s > 0; s >>= 1) {
        if (threadIdx.x < s) red[threadIdx.x] = fmaxf(red[threadIdx.x], red[threadIdx.x + s]);
        __syncthreads();
    }
    if (threadIdx.x == 0) out[0] = 50.0f / red[0];
}

// ---------------------------------------------------------------------------
// GEMM kernel v7: LDS-staged, distinct-optimal issued loads.
// Evidence: baseline/v2/v4/v6 all ~18 us/step across wildly different cache
// traffic and occupancy -> the invariant was ISSUED vector loads (~320
// MB/step from 4x A-fragment redundancy). v7 stages each 32-k chunk's
// distinct 16 KB (A 8 KB + B 8 KB) into a single 16 KB LDS buffer via
// cooperative reg-staging (issue-early/write-late, 2 barriers/chunk), then
// waves read fragments with ds_read_b128. Issued loads: 128 MB/step.
// Grid 512 = 64 strips x 8 K-eighths (2 blocks/CU); 8 waves: nq=w&3
// (16-col group), mh=w>>2 (m-half, 2 mq subtiles), FULL 512-k range per
// wave -> acc is final, direct P store, no LDS reduction. No cross-block
// sync (v3: fence+atomic = 180 us/step; kernel boundary is the barrier).
// ---------------------------------------------------------------------------
__global__ __launch_bounds__(512, 4) void gemm_kernel(
    const unsigned short* __restrict__ gfh,
    const unsigned short* __restrict__ gfl,
    const unsigned short* __restrict__ Wfh,
    const unsigned short* __restrict__ Wfl,
    float* __restrict__ P)                    // [8][64][64][64] fp32 partials
{
    // 16 KB: elems [0,2048) Ah | [2048,4096) Al | [4096+nq*512) Bh | [6144+nq*512) Bl
    __shared__ unsigned short lds[8192];

    const int tid  = threadIdx.x;
    const int w    = tid >> 6;                // 0..7
    const int lane = tid & 63;
    const int s64  = blockIdx.x >> 3;         // 64-col strip 0..63
    const int kq8  = blockIdx.x & 7;          // K-eighth 0..7 (512 k = 16 chunks)
    const int nq   = w & 3;                   // wave's 16-col group in strip
    const int mh   = w >> 2;                  // wave's m-half (2 mq subtiles)

    // Staging map: thread t moves 32 B/chunk as two 16 B pieces.
    //  piece 1 -> lds elem t*8        : t<256 from gfh (elem t*8), else gfl
    //  piece 2 -> lds elem 4096+t*8   : t<256 from Wfh, else Wfl; nq2=(t&255)>>6
    const int tA  = (tid & 255) * 8;          // A elem within chunk
    const int nq2 = (tid & 255) >> 6;
    const int eB  = (tid & 63) * 8;           // B elem within (nq2, chunk)
    const unsigned short* __restrict__ srcA = (tid < 256) ? gfh : gfl;
    const unsigned short* __restrict__ srcB = (tid < 256) ? Wfh : Wfl;
    const size_t bRow = (size_t)(s64 * 4 + nq2) * 128;   // + kc, then *512

    f32x4 acc[2] = {};                        // 2 m-subtiles x (16x16) frag

    // Prologue: stage chunk 0.
    {
        const int kc = kq8 * 16;
        uint4 rA = *(const uint4*)&srcA[(size_t)kc * 2048 + tA];
        uint4 rB = *(const uint4*)&srcB[(bRow + kc) * 512 + eB];
        *(uint4*)&lds[tid * 8]        = rA;
        *(uint4*)&lds[4096 + tid * 8] = rB;
    }
    __syncthreads();

    for (int it = 0; it < 16; ++it) {
        // Issue next chunk's global loads early (latency hides under MFMA).
        uint4 nA, nB;
        if (it < 15) {
            const int kcn = kq8 * 16 + it + 1;
            nA = *(const uint4*)&srcA[(size_t)kcn * 2048 + tA];
            nB = *(const uint4*)&srcB[(bRow + kcn) * 512 + eB];
        }

        // Fragment reads from LDS + MFMA (current chunk).
        bf16x8 bh = *(const bf16x8*)&lds[4096 + nq * 512 + lane * 8];
        bf16x8 bl = *(const bf16x8*)&lds[6144 + nq * 512 + lane * 8];
#pragma unroll
        for (int f = 0; f < 2; ++f) {
            const int mq = mh * 2 + f;
            bf16x8 ah = *(const bf16x8*)&lds[mq * 512 + lane * 8];
            bf16x8 al = *(const bf16x8*)&lds[2048 + mq * 512 + lane * 8];
            acc[f] = __builtin_amdgcn_mfma_f32_16x16x32_bf16(ah, bh, acc[f], 0, 0, 0);
            acc[f] = __builtin_amdgcn_mfma_f32_16x16x32_bf16(al, bh, acc[f], 0, 0, 0);
            acc[f] = __builtin_amdgcn_mfma_f32_16x16x32_bf16(ah, bl, acc[f], 0, 0, 0);
        }

        __syncthreads();                      // all waves done reading buffer
        if (it < 15) {
            *(uint4*)&lds[tid * 8]        = nA;
            *(uint4*)&lds[4096 + tid * 8] = nB;
        }
        __syncthreads();                      // buffer ready for next chunk
    }

    // Direct P store: wave's acc is the complete K-eighth partial.
    // C-frag layout: value(row16=q*4+rg, col=l16) at lane q*16+l16, reg rg.
    {
        const int q = lane >> 4, l16 = lane & 15;
        float* Pb = &P[(size_t)(kq8 * 64 + s64) * 4096];
#pragma unroll
        for (int f = 0; f < 2; ++f) {
            const int mq = mh * 2 + f;
#pragma unroll
            for (int rg = 0; rg < 4; ++rg) {
                const int m = mq * 16 + q * 4 + rg;
                Pb[(size_t)m * 64 + nq * 16 + l16] = acc[f][rg];
            }
        }
    }
}

// ---------------------------------------------------------------------------
// Epilogue kernel: grid 256 x 256 thr; block b -> strip s64 = b>>2,
// row-quarter mq4 = b&3. Thread t: row, 4 cols. Sums 8 K-eighth partials,
// applies b/alpha/clip/sigmoid, updates x, writes next-step A-fragments.
// Cross-kernel P visibility via the dispatch boundary (baseline-proven).
// ---------------------------------------------------------------------------
__global__ __launch_bounds__(256) void epi_kernel(
    const float* __restrict__ P,
    float* __restrict__ x,
    unsigned short* __restrict__ gfh_out,
    unsigned short* __restrict__ gfl_out,
    const float* __restrict__ bvec,
    const float* __restrict__ beta,
    const float* __restrict__ tau,
    const float* __restrict__ dt_ptr,
    const float* __restrict__ maxx_ptr,
    float* __restrict__ gout_f32)             // non-null on last step only
{
    const int tid = threadIdx.x;
    const int s64 = blockIdx.x >> 2;
    const int mq4 = blockIdx.x & 3;
    const int m   = mq4 * 16 + (tid >> 4);    // batch row 0..63
    const int tt  = tid & 15;
    const int c0  = tt * 4;
    const int n0  = s64 * 64 + c0;            // global col, 4-aligned

    const size_t pb = ((size_t)s64 * 64 + m) * 64 + c0;
    float sum[4] = {};
#pragma unroll
    for (int k8 = 0; k8 < 8; ++k8) {
        float4 p = *(const float4*)&P[(size_t)k8 * 262144 + pb];
        sum[0] += p.x; sum[1] += p.y; sum[2] += p.z; sum[3] += p.w;
    }

    const float dt = *dt_ptr;
    const float mx = *maxx_ptr;
    float4 b0 = *(const float4*)&bvec[n0];
    float4 e0 = *(const float4*)&beta[n0];
    float4 t0 = *(const float4*)&tau[n0];
    float bb[4] = {b0.x, b0.y, b0.z, b0.w};
    float be[4] = {e0.x, e0.y, e0.z, e0.w};
    float tv[4] = {t0.x, t0.y, t0.z, t0.w};

    float* xp = &x[(size_t)m * NN + n0];
    float4 x0 = *(const float4*)xp;
    float xo[4] = {x0.x, x0.y, x0.z, x0.w};

    float gg[4];
    unsigned short vh[4], vl[4];
#pragma unroll
    for (int j = 0; j < 4; ++j) {
        const float al = dt / tv[j];
        float xn = al * (sum[j] + bb[j]) + (1.0f - al) * xo[j];
        xn = fminf(fmaxf(xn, -mx), mx);
        float g = 1.0f / (1.0f + __expf(-be[j] * xn));
        xo[j] = xn;
        gg[j] = g;
        unsigned short hi = f2bf(g);
        vh[j] = hi;
        vl[j] = f2bf(g - bf2f(hi));
    }
    *(float4*)xp = {xo[0], xo[1], xo[2], xo[3]};

    // A-fragment scatter for (m, kg = n0..n0+3); n0%8 in {0,4} -> ushort4.
    size_t off = (((size_t)(n0 >> 5) * 4 + (m >> 4)) * 64 + ((n0 & 31) >> 3) * 16 + (m & 15)) * 8 + (n0 & 7);
    *(ushort4*)&gfh_out[off] = {vh[0], vh[1], vh[2], vh[3]};
    *(ushort4*)&gfl_out[off] = {vl[0], vl[1], vl[2], vl[3]};

    if (gout_f32)
        *(float4*)&gout_f32[(size_t)m * NN + n0] = {gg[0], gg[1], gg[2], gg[3]};
}

// ---------------------------------------------------------------------------
extern "C" void kernel_launch(void* const* d_in, const int* in_sizes, int n_in,
                              void* d_out, int out_size, void* d_ws, size_t ws_size,
                              hipStream_t stream) {
    const float* state_g = (const float*)d_in[0];
    const float* W       = (const float*)d_in[1];
    const float* b       = (const float*)d_in[2];
    const float* beta    = (const float*)d_in[3];
    const float* tau     = (const float*)d_in[4];
    const float* dt      = (const float*)d_in[5];
    float* out = (float*)d_out;

    char* ws = (char*)d_ws;
    const size_t WH = (size_t)KK * NN * 2;    // 32 MB per W-frag array
    const size_t XB = (size_t)MM * NN * 4;    // 1 MB
    const size_t GB = (size_t)MM * NN * 2;    // 512 KB per g-frag array
    const size_t PB = (size_t)8 * 64 * 64 * 64 * 4;   // 8 MB partials
    unsigned short* Wfh = (unsigned short*)ws;
    unsigned short* Wfl = (unsigned short*)(ws + WH);
    float*          x   = (float*)(ws + 2 * WH);
    unsigned short* g0h = (unsigned short*)(ws + 2 * WH + XB);
    unsigned short* g0l = (unsigned short*)(ws + 2 * WH + XB + GB);
    unsigned short* g1h = (unsigned short*)(ws + 2 * WH + XB + 2 * GB);
    unsigned short* g1l = (unsigned short*)(ws + 2 * WH + XB + 3 * GB);
    float*          P   = (float*)(ws + 2 * WH + XB + 4 * GB);
    float*          mxp = (float*)(ws + 2 * WH + XB + 4 * GB + PB);

    symm_kernel<<<dim3(64, 64), 256, 0, stream>>>(W, Wfh, Wfl);
    init_kernel<<<(MM * NN) / 256, 256, 0, stream>>>(state_g, beta, x, g0h, g0l);
    maxx_kernel<<<1, 256, 0, stream>>>(beta, mxp);

    unsigned short *gih = g0h, *gil = g0l, *goh = g1h, *gol = g1l;
    for (int st = 0; st < NSTEP; ++st) {
        float* of = (st == NSTEP - 1) ? out : nullptr;
        gemm_kernel<<<512, 512, 0, stream>>>(gih, gil, Wfh, Wfl, P);
        epi_kernel<<<256, 256, 0, stream>>>(P, x, goh, gol, b, beta, tau, dt, mxp, of);
        unsigned short* tp;
        tp = gih; gih = goh; goh = tp;
        tp = gil; gil = gol; gol = tp;
    }
}